// Round 9
// baseline (435.020 us; speedup 1.0000x reference)
//
#include <hip/hip_runtime.h>
#include <math.h>

// Problem constants (fixed by reference file)
#define LQ      37440
#define LIN     37440     // 32^3 + 16^3 + 8^3 + 4^3
#define DMODEL  256
#define NHEADS  8
#define CHEAD   32
#define K_DIM   256

typedef __attribute__((ext_vector_type(8))) short short8;
typedef __attribute__((ext_vector_type(4))) short short4v;
typedef __attribute__((ext_vector_type(4))) float f32x4;
typedef __attribute__((ext_vector_type(2))) float f32x2;

__device__ inline unsigned short bf16_rte(float f) {
    union { float f; unsigned u; } v; v.f = f;
    return (unsigned short)((v.u + 0x7fffu + ((v.u >> 16) & 1u)) >> 16);
}
__device__ inline float bf16_f(unsigned short s) {
    union { unsigned u; float f; } v; v.u = ((unsigned)s) << 16;
    return v.f;
}
__device__ inline float bits_f(unsigned u) {
    union { unsigned u; float f; } v; v.u = u;
    return v.f;
}
__device__ inline unsigned pkbf(float a, float b) {
    return (unsigned)bf16_rte(a) | ((unsigned)bf16_rte(b) << 16);
}

// -------------------------------------------------------------------------
// prep_all: activations fp32->bf16 AND all weight transposes + bias concat
// in ONE launch. Blocks [0, 18720): acts (inp then query, n4 float4 each);
// blocks [18720, 19744): 1024 virtual weight rows x 256 k.
// -------------------------------------------------------------------------
__global__ __launch_bounds__(256) void prep_all(
        const float* __restrict__ inp, const float* __restrict__ query,
        const float* __restrict__ Wv, const float* __restrict__ Wo,
        const float* __restrict__ Wa, const float* __restrict__ Wout,
        const float* __restrict__ bo, const float* __restrict__ ba,
        unsigned short* __restrict__ in_b, unsigned short* __restrict__ q_b,
        unsigned short* __restrict__ Bv, unsigned short* __restrict__ Bq,
        unsigned short* __restrict__ Bw, float* __restrict__ bias_m, int n4)
{
    const int bid = blockIdx.x;
    if (bid < 18720) {
        int i = bid * 256 + threadIdx.x;   // over 2*n4
        const float* src;
        unsigned short* dst;
        int j;
        if (i < n4) { src = inp;   dst = in_b; j = i; }
        else        { src = query; dst = q_b;  j = i - n4; }
        float4 v = ((const float4*)src)[j];
        short4v h;
        h.x = (short)bf16_rte(v.x);
        h.y = (short)bf16_rte(v.y);
        h.z = (short)bf16_rte(v.z);
        h.w = (short)bf16_rte(v.w);
        ((short4v*)dst)[j] = h;
    } else {
        int i = (bid - 18720) * 256 + threadIdx.x;
        int n = i >> 8, k = i & 255;
        if (n < 256) {
            Bv[(size_t)n * 256 + k] = bf16_rte(Wv[(size_t)k * 256 + n]);
        } else if (n < 640) {
            int m = n - 256;
            Bq[(size_t)m * 256 + k] = bf16_rte(Wo[(size_t)k * 384 + m]);
        } else if (n < 768) {
            int m = n - 640;
            Bq[(size_t)(384 + m) * 256 + k] = bf16_rte(Wa[(size_t)k * 128 + m]);
        } else {
            int m = n - 768;
            Bw[(size_t)m * 256 + k] = bf16_rte(Wout[(size_t)k * 256 + m]);
        }
        if (i < 512) bias_m[i] = (i < 384) ? bo[i] : ba[i - 384];
    }
}

// -------------------------------------------------------------------------
// Fused value+qbuf GEMM, LDS-staged. BM=128, BN=128, BK=32. (r8, verified)
// grid = (6, 293): x 0-1 -> value = in_b @ Bv (head-major bf16);
//                  x 2-5 -> qbuf = q_b @ Bq (row-major bf16, N=512).
// -------------------------------------------------------------------------
__global__ __launch_bounds__(256) void gemm2(
    const unsigned short* __restrict__ in_b, const unsigned short* __restrict__ q_b,
    const unsigned short* __restrict__ Bv,   const unsigned short* __restrict__ Bq,
    const float* __restrict__ bv, const float* __restrict__ bias_m,
    unsigned short* __restrict__ value_t, unsigned short* __restrict__ qbuf)
{
    __shared__ __align__(16) unsigned short As[128][40];
    __shared__ __align__(16) unsigned short Bs[128][40];

    const int t    = threadIdx.x;
    const int bm   = blockIdx.y * 128;
    const int w    = t >> 6;
    const int lane = t & 63;
    const int lm   = lane & 15;
    const int quad = lane >> 4;

    const int isval = (blockIdx.x < 2);
    const unsigned short* A  = isval ? in_b : q_b;
    const unsigned short* Bt = isval ? Bv : Bq;
    const float* bias        = isval ? bv : bias_m;
    const int n0             = (isval ? blockIdx.x : (blockIdx.x - 2)) * 128;

    const int s_row = t >> 1;
    const int s_k   = (t & 1) << 4;

    int arow_g = bm + s_row; if (arow_g >= LQ) arow_g = LQ - 1;
    const size_t a_off = (size_t)arow_g * K_DIM + s_k;
    const size_t b_off = (size_t)(n0 + s_row) * K_DIM + s_k;

    f32x4 acc[2][8];
    #pragma unroll
    for (int mt = 0; mt < 2; ++mt)
        #pragma unroll
        for (int nt = 0; nt < 8; ++nt)
            acc[mt][nt] = (f32x4){0.f, 0.f, 0.f, 0.f};

    for (int k0 = 0; k0 < K_DIM; k0 += 32) {
        int4 a0 = *(const int4*)(A + a_off + k0);
        int4 a1 = *(const int4*)(A + a_off + k0 + 8);
        int4 b0 = *(const int4*)(Bt + b_off + k0);
        int4 b1 = *(const int4*)(Bt + b_off + k0 + 8);
        __syncthreads();
        *(int4*)&As[s_row][s_k]     = a0;
        *(int4*)&As[s_row][s_k + 8] = a1;
        *(int4*)&Bs[s_row][s_k]     = b0;
        *(int4*)&Bs[s_row][s_k + 8] = b1;
        __syncthreads();

        short8 af[2], bf[8];
        #pragma unroll
        for (int mt = 0; mt < 2; ++mt)
            af[mt] = *(const short8*)&As[w * 32 + mt * 16 + lm][quad * 8];
        #pragma unroll
        for (int nt = 0; nt < 8; ++nt)
            bf[nt] = *(const short8*)&Bs[nt * 16 + lm][quad * 8];
        #pragma unroll
        for (int mt = 0; mt < 2; ++mt)
            #pragma unroll
            for (int nt = 0; nt < 8; ++nt)
                acc[mt][nt] = __builtin_amdgcn_mfma_f32_16x16x32_bf16(af[mt], bf[nt], acc[mt][nt], 0, 0, 0);
    }

    #pragma unroll
    for (int nt = 0; nt < 8; ++nt) {
        int col = n0 + nt * 16 + lm;
        float bb = bias[col];
        #pragma unroll
        for (int mt = 0; mt < 2; ++mt)
            #pragma unroll
            for (int r = 0; r < 4; ++r) {
                int row = bm + w * 32 + mt * 16 + quad * 4 + r;
                if (row < LQ) {
                    float o = acc[mt][nt][r] + bb;
                    if (isval) {
                        int h = col >> 5, c = col & 31;
                        value_t[((size_t)h * LIN + row) * 32 + c] = bf16_rte(o);
                    } else {
                        qbuf[(size_t)row * 512 + col] = bf16_rte(o);
                    }
                }
            }
    }
}

// -------------------------------------------------------------------------
// Sampling kernel v4: v3 gather (x-corner pair fusion, verified) + FUSED
// output projection on the idle MFMA pipe.
// Phases 1/2 identical to r8. Phase 3: the block's 4 samp rows (4 x 256
// bf16) are staged in LDS (aliasing the dead zyw/wx region, layout
// [ch8][row][8] -> 2-way-conflict-free b128 reads); each wave then runs
// 32 MFMAs (16x16x32) vs L2-resident Bw to produce out[q0..q0+3][w*64..+64).
// A rows 4-15 are stale LDS garbage: MFMA C row m depends only on A row m,
// and rows >= 4 of C are discarded, so no zero-padding is needed.
// -------------------------------------------------------------------------
__global__ __launch_bounds__(256) void sample_kernel(
    const float* __restrict__ refp,              // (LQ, 4, 3) fp32
    const unsigned short* __restrict__ qbuf,     // (LQ, 512) bf16
    const unsigned short* __restrict__ value_t,  // (8, LIN, 32) bf16 head-major
    const unsigned short* __restrict__ Bw,       // (256, 256) bf16 = Wout^T
    const float* __restrict__ bout,              // (256,) fp32
    float* __restrict__ outp)                    // (LQ, 256) fp32
{
    __shared__ union {
        struct {
            float4 zyw[4][16][8];   // zy corner cross-weights   8 KB
            f32x2  wx [4][16][8];   // (wx0, wx1) * a            4 KB
        } g;
        unsigned short sampA[32][16][8];  // [ch8-block][row][ch] 8 KB (phase 3)
    } U;
    __shared__ int4   ozyS[4][16][8];   // zy offsets * 32 (shorts)  8 KB
    __shared__ int    xbS [4][16][8];   // x0 * 32 (shorts, signed)  2 KB
    __shared__ float  lg  [4][128];     // logits                    2 KB

    const int t  = threadIdx.x;
    const int q0 = blockIdx.x * 4;

    const int   Sz[4]   = {32, 16, 8, 4};
    const float invS[4] = {1.f/32.f, 1.f/16.f, 1.f/8.f, 1.f/4.f};
    const int   St[4]   = {0, 32768, 36864, 37376};

    // Phase 1: geometry
    #pragma unroll
    for (int pi = t; pi < 512; pi += 256) {
        int ql = pi >> 7;
        int hp = pi & 127;          // hh*16 + c, c = l*4+p
        int hh = hp >> 4;
        int c  = hp & 15;
        int l  = c >> 2;
        int q  = q0 + ql;
        const unsigned short* o = qbuf + (size_t)q * 512 + hp * 3;
        const float* r = refp + q * 12 + l * 3;
        const int   S  = Sz[l];
        const float Sf = (float)S;
        const float is = invS[l];
        float ix = (r[0] + bf16_f(o[0]) * is) * Sf - 0.5f;
        float iy = (r[1] + bf16_f(o[1]) * is) * Sf - 0.5f;
        float iz = (r[2] + bf16_f(o[2]) * is) * Sf - 0.5f;
        float xf = floorf(ix), yf = floorf(iy), zf = floorf(iz);
        float fx = ix - xf, fy = iy - yf, fz = iz - zf;
        int x0 = (int)xf, y0 = (int)yf, z0 = (int)zf;

        float wx0 = (x0 >= 0  && x0 < S)     ? (1.f - fx) : 0.f;
        float wx1 = (x0 >= -1 && x0 < S - 1) ? fx         : 0.f;
        float wy0 = (y0 >= 0  && y0 < S)     ? (1.f - fy) : 0.f;
        float wy1 = (y0 >= -1 && y0 < S - 1) ? fy         : 0.f;
        float wz0 = (z0 >= 0  && z0 < S)     ? (1.f - fz) : 0.f;
        float wz1 = (z0 >= -1 && z0 < S - 1) ? fz         : 0.f;

        int cy0 = min(max(y0, 0), S - 1), cy1 = min(max(y0 + 1, 0), S - 1);
        int cz0 = min(max(z0, 0), S - 1), cz1 = min(max(z0 + 1, 0), S - 1);

        const int S2 = S * S;
        const int st = St[l];
        U.g.zyw[ql][c][hh] = make_float4(wz0*wy0, wz0*wy1, wz1*wy0, wz1*wy1);
        U.g.wx [ql][c][hh] = (f32x2){wx0, wx1};
        ozyS[ql][c][hh] = make_int4((st + cz0*S2 + cy0*S) * 32,
                                    (st + cz0*S2 + cy1*S) * 32,
                                    (st + cz1*S2 + cy0*S) * 32,
                                    (st + cz1*S2 + cy1*S) * 32);
        xbS [ql][c][hh] = x0 * 32;   // may be -32 .. (S-1)*32
        lg[ql][hp] = bf16_f(qbuf[(size_t)q * 512 + 384 + hp]);
    }
    __syncthreads();

    // Phase 1b: softmax over 16 points per (q_local, head); fold a into wx
    #pragma unroll
    for (int pi = t; pi < 512; pi += 256) {
        int ql = pi >> 7;
        int hp = pi & 127;
        int hh = hp >> 4;
        int c  = hp & 15;
        const float* L = &lg[ql][hh << 4];
        float m = L[0];
        #pragma unroll
        for (int j = 1; j < 16; ++j) m = fmaxf(m, L[j]);
        float s = 0.f;
        #pragma unroll
        for (int j = 0; j < 16; ++j) s += expf(L[j] - m);
        float a = expf(lg[ql][hp] - m) / s;
        f32x2 wv = U.g.wx[ql][c][hh];
        U.g.wx[ql][c][hh] = (f32x2){wv.x * a, wv.y * a};
    }
    __syncthreads();

    // Phase 2: gather + weighted accumulate. 64 lanes = 8 heads x 8 lanes.
    const int ql   = t >> 6;          // wave index == local query
    const int lane = t & 63;
    const int hh   = lane >> 3;
    const int j    = lane & 7;
    const int xsel = j >> 2;          // 0: x0 half, 1: x1 half
    const int jj   = j & 3;           // channel group (8 ch) within head
    const unsigned short* vt = value_t + (size_t)hh * LIN * 32 + j * 8;

    f32x2 acc0 = {0.f,0.f}, acc1 = {0.f,0.f}, acc2 = {0.f,0.f}, acc3 = {0.f,0.f};

    #pragma unroll
    for (int c = 0; c < 16; ++c) {
        float4 zyw = U.g.zyw[ql][c][hh];
        f32x2  wx  = U.g.wx [ql][c][hh];
        int4   zo  = ozyS[ql][c][hh];
        int    xb  = xbS [ql][c][hh];
        float  ws  = xsel ? wx.y : wx.x;
        const unsigned short* bp = vt + xb;

        #define CORNER(OFF, WZ) { \
            int4 v = *(const int4*)(bp + (OFF)); \
            float w_ = (WZ) * ws; \
            f32x2 w2 = {w_, w_}; \
            acc0 += w2 * (f32x2){bits_f(((unsigned)v.x) << 16), bits_f((unsigned)v.x & 0xffff0000u)}; \
            acc1 += w2 * (f32x2){bits_f(((unsigned)v.y) << 16), bits_f((unsigned)v.y & 0xffff0000u)}; \
            acc2 += w2 * (f32x2){bits_f(((unsigned)v.z) << 16), bits_f((unsigned)v.z & 0xffff0000u)}; \
            acc3 += w2 * (f32x2){bits_f(((unsigned)v.w) << 16), bits_f((unsigned)v.w & 0xffff0000u)}; }

        CORNER(zo.x, zyw.x);
        CORNER(zo.y, zyw.y);
        CORNER(zo.z, zyw.z);
        CORNER(zo.w, zyw.w);
        #undef CORNER
    }

    // Combine x0/x1 halves across lane^4, pack to bf16
    float c0 = acc0.x + __shfl_xor(acc0.x, 4);
    float c1 = acc0.y + __shfl_xor(acc0.y, 4);
    float c2 = acc1.x + __shfl_xor(acc1.x, 4);
    float c3 = acc1.y + __shfl_xor(acc1.y, 4);
    float c4 = acc2.x + __shfl_xor(acc2.x, 4);
    float c5 = acc2.y + __shfl_xor(acc2.y, 4);
    float c6 = acc3.x + __shfl_xor(acc3.x, 4);
    float c7 = acc3.y + __shfl_xor(acc3.y, 4);
    int4 o = make_int4((int)pkbf(c0, c1), (int)pkbf(c2, c3),
                       (int)pkbf(c4, c5), (int)pkbf(c6, c7));

    // Phase 3: stage samp rows in LDS (aliases dead zyw/wx region), then
    // fused projection: out[q0+m][:] = samp[m][:] @ Bw' + bout on MFMA pipe.
    __syncthreads();                 // all reads of U.g / shfl done
    if (xsel == 0)
        *(int4*)&U.sampA[hh * 4 + jj][ql][0] = o;   // ch-block hh*4+jj, row ql
    __syncthreads();

    const int n0w = ql * 64;         // wave's 64-col slice of the output
    f32x4 pacc[4];
    #pragma unroll
    for (int nt = 0; nt < 4; ++nt) pacc[nt] = (f32x4){0.f, 0.f, 0.f, 0.f};

    const int lm   = lane & 15;
    const int quad = lane >> 4;
    #pragma unroll
    for (int s = 0; s < 8; ++s) {
        short8 a = *(const short8*)&U.sampA[s * 4 + quad][lm][0];
        #pragma unroll
        for (int nt = 0; nt < 4; ++nt) {
            short8 b = *(const short8*)(Bw + (size_t)(n0w + nt * 16 + lm) * 256 + s * 32 + quad * 8);
            pacc[nt] = __builtin_amdgcn_mfma_f32_16x16x32_bf16(a, b, pacc[nt], 0, 0, 0);
        }
    }

    if (quad == 0) {                 // C rows 0..3 live in quad 0
        #pragma unroll
        for (int nt = 0; nt < 4; ++nt) {
            int col = n0w + nt * 16 + lm;
            float bb = bout[col];
            #pragma unroll
            for (int r = 0; r < 4; ++r)
                outp[(size_t)(q0 + r) * DMODEL + col] = pacc[nt][r] + bb;
        }
    }
}

// -------------------------------------------------------------------------
// 3 launches: prep_all, gemm2 (value+qbuf), sample_kernel (gather + fused
// output projection).
// Workspace (~96.5 MB): pad 256B | value_t 19.2 | qbuf 38.3 | in_b 19.2 |
// q_b 19.2 | Bv/Bq/Bw/bias ~0.55 MB
// -------------------------------------------------------------------------
extern "C" void kernel_launch(void* const* d_in, const int* in_sizes, int n_in,
                              void* d_out, int out_size, void* d_ws, size_t ws_size,
                              hipStream_t stream) {
    const float* query = (const float*)d_in[0];
    const float* refp  = (const float*)d_in[1];
    const float* inp   = (const float*)d_in[2];
    const float* Wv   = (const float*)d_in[5];
    const float* bv   = (const float*)d_in[6];
    const float* Wo   = (const float*)d_in[7];
    const float* bo   = (const float*)d_in[8];
    const float* Wa   = (const float*)d_in[9];
    const float* ba   = (const float*)d_in[10];
    const float* Wout = (const float*)d_in[11];
    const float* bout = (const float*)d_in[12];

    char* p = (char*)d_ws;
    p += 256;                                     // underflow pad
    unsigned short* value_t = (unsigned short*)p; p += (size_t)LIN * 256 * 2;
    unsigned short* qbuf    = (unsigned short*)p; p += (size_t)LQ * 512 * 2;
    unsigned short* in_b    = (unsigned short*)p; p += (size_t)LQ * 256 * 2;
    unsigned short* q_b     = (unsigned short*)p; p += (size_t)LQ * 256 * 2;
    unsigned short* Bv   = (unsigned short*)p;    p += 256 * 256 * 2;
    unsigned short* Bq   = (unsigned short*)p;    p += 512 * 256 * 2;
    unsigned short* Bw   = (unsigned short*)p;    p += 256 * 256 * 2;
    float* bias_m = (float*)p;                    p += 512 * 4;

    const int n4 = LQ * 256 / 4;   // 2,396,160
    dim3 blk(256);

    // 1) all prep: activations fp32->bf16 + weight transposes + bias concat
    prep_all<<<18720 + 1024, blk, 0, stream>>>(
        inp, query, Wv, Wo, Wa, Wout, bo, ba,
        in_b, q_b, Bv, Bq, Bw, bias_m, n4);
    // 2) value (head-major) + off/attn (qbuf) in one launch
    gemm2<<<dim3(6, (LQ + 127) / 128), blk, 0, stream>>>(
        in_b, q_b, Bv, Bq, bv, bias_m, value_t, qbuf);
    // 3) sampling + softmax + weighted sum + fused output projection
    sample_kernel<<<LQ / 4, blk, 0, stream>>>(
        refp, qbuf, value_t, Bw, bout, (float*)d_out);
}

// Round 10
// 353.685 us; speedup vs baseline: 1.2300x; 1.2300x over previous
//
#include <hip/hip_runtime.h>
#include <math.h>

// Problem constants (fixed by reference file)
#define LQ      37440
#define LIN     37440     // 32^3 + 16^3 + 8^3 + 4^3
#define DMODEL  256
#define NHEADS  8
#define CHEAD   32
#define K_DIM   256

typedef __attribute__((ext_vector_type(8))) short short8;
typedef __attribute__((ext_vector_type(4))) short short4v;
typedef __attribute__((ext_vector_type(4))) float f32x4;
typedef __attribute__((ext_vector_type(2))) float f32x2;

__device__ inline unsigned short bf16_rte(float f) {
    union { float f; unsigned u; } v; v.f = f;
    return (unsigned short)((v.u + 0x7fffu + ((v.u >> 16) & 1u)) >> 16);
}
__device__ inline float bf16_f(unsigned short s) {
    union { unsigned u; float f; } v; v.u = ((unsigned)s) << 16;
    return v.f;
}
__device__ inline float bits_f(unsigned u) {
    union { unsigned u; float f; } v; v.u = u;
    return v.f;
}
__device__ inline unsigned pkbf(float a, float b) {
    return (unsigned)bf16_rte(a) | ((unsigned)bf16_rte(b) << 16);
}

// -------------------------------------------------------------------------
// prep_all: activations fp32->bf16 AND all weight transposes + bias concat
// in ONE launch (verified r9). Blocks [0, 18720): acts; rest: weights.
// -------------------------------------------------------------------------
__global__ __launch_bounds__(256) void prep_all(
        const float* __restrict__ inp, const float* __restrict__ query,
        const float* __restrict__ Wv, const float* __restrict__ Wo,
        const float* __restrict__ Wa, const float* __restrict__ Wout,
        const float* __restrict__ bo, const float* __restrict__ ba,
        unsigned short* __restrict__ in_b, unsigned short* __restrict__ q_b,
        unsigned short* __restrict__ Bv, unsigned short* __restrict__ Bq,
        unsigned short* __restrict__ Bw, float* __restrict__ bias_m, int n4)
{
    const int bid = blockIdx.x;
    if (bid < 18720) {
        int i = bid * 256 + threadIdx.x;   // over 2*n4
        const float* src;
        unsigned short* dst;
        int j;
        if (i < n4) { src = inp;   dst = in_b; j = i; }
        else        { src = query; dst = q_b;  j = i - n4; }
        float4 v = ((const float4*)src)[j];
        short4v h;
        h.x = (short)bf16_rte(v.x);
        h.y = (short)bf16_rte(v.y);
        h.z = (short)bf16_rte(v.z);
        h.w = (short)bf16_rte(v.w);
        ((short4v*)dst)[j] = h;
    } else {
        int i = (bid - 18720) * 256 + threadIdx.x;
        int n = i >> 8, k = i & 255;
        if (n < 256) {
            Bv[(size_t)n * 256 + k] = bf16_rte(Wv[(size_t)k * 256 + n]);
        } else if (n < 640) {
            int m = n - 256;
            Bq[(size_t)m * 256 + k] = bf16_rte(Wo[(size_t)k * 384 + m]);
        } else if (n < 768) {
            int m = n - 640;
            Bq[(size_t)(384 + m) * 256 + k] = bf16_rte(Wa[(size_t)k * 128 + m]);
        } else {
            int m = n - 768;
            Bw[(size_t)m * 256 + k] = bf16_rte(Wout[(size_t)k * 256 + m]);
        }
        if (i < 512) bias_m[i] = (i < 384) ? bo[i] : ba[i - 384];
    }
}

// -------------------------------------------------------------------------
// Fused value+qbuf GEMM, LDS-staged. BM=128, BN=128, BK=32. (r8, verified)
// grid = (6, 293): x 0-1 -> value = in_b @ Bv (head-major bf16);
//                  x 2-5 -> qbuf = q_b @ Bq (row-major bf16, N=512).
// -------------------------------------------------------------------------
__global__ __launch_bounds__(256) void gemm2(
    const unsigned short* __restrict__ in_b, const unsigned short* __restrict__ q_b,
    const unsigned short* __restrict__ Bv,   const unsigned short* __restrict__ Bq,
    const float* __restrict__ bv, const float* __restrict__ bias_m,
    unsigned short* __restrict__ value_t, unsigned short* __restrict__ qbuf)
{
    __shared__ __align__(16) unsigned short As[128][40];
    __shared__ __align__(16) unsigned short Bs[128][40];

    const int t    = threadIdx.x;
    const int bm   = blockIdx.y * 128;
    const int w    = t >> 6;
    const int lane = t & 63;
    const int lm   = lane & 15;
    const int quad = lane >> 4;

    const int isval = (blockIdx.x < 2);
    const unsigned short* A  = isval ? in_b : q_b;
    const unsigned short* Bt = isval ? Bv : Bq;
    const float* bias        = isval ? bv : bias_m;
    const int n0             = (isval ? blockIdx.x : (blockIdx.x - 2)) * 128;

    const int s_row = t >> 1;
    const int s_k   = (t & 1) << 4;

    int arow_g = bm + s_row; if (arow_g >= LQ) arow_g = LQ - 1;
    const size_t a_off = (size_t)arow_g * K_DIM + s_k;
    const size_t b_off = (size_t)(n0 + s_row) * K_DIM + s_k;

    f32x4 acc[2][8];
    #pragma unroll
    for (int mt = 0; mt < 2; ++mt)
        #pragma unroll
        for (int nt = 0; nt < 8; ++nt)
            acc[mt][nt] = (f32x4){0.f, 0.f, 0.f, 0.f};

    for (int k0 = 0; k0 < K_DIM; k0 += 32) {
        int4 a0 = *(const int4*)(A + a_off + k0);
        int4 a1 = *(const int4*)(A + a_off + k0 + 8);
        int4 b0 = *(const int4*)(Bt + b_off + k0);
        int4 b1 = *(const int4*)(Bt + b_off + k0 + 8);
        __syncthreads();
        *(int4*)&As[s_row][s_k]     = a0;
        *(int4*)&As[s_row][s_k + 8] = a1;
        *(int4*)&Bs[s_row][s_k]     = b0;
        *(int4*)&Bs[s_row][s_k + 8] = b1;
        __syncthreads();

        short8 af[2], bf[8];
        #pragma unroll
        for (int mt = 0; mt < 2; ++mt)
            af[mt] = *(const short8*)&As[w * 32 + mt * 16 + lm][quad * 8];
        #pragma unroll
        for (int nt = 0; nt < 8; ++nt)
            bf[nt] = *(const short8*)&Bs[nt * 16 + lm][quad * 8];
        #pragma unroll
        for (int mt = 0; mt < 2; ++mt)
            #pragma unroll
            for (int nt = 0; nt < 8; ++nt)
                acc[mt][nt] = __builtin_amdgcn_mfma_f32_16x16x32_bf16(af[mt], bf[nt], acc[mt][nt], 0, 0, 0);
    }

    #pragma unroll
    for (int nt = 0; nt < 8; ++nt) {
        int col = n0 + nt * 16 + lm;
        float bb = bias[col];
        #pragma unroll
        for (int mt = 0; mt < 2; ++mt)
            #pragma unroll
            for (int r = 0; r < 4; ++r) {
                int row = bm + w * 32 + mt * 16 + quad * 4 + r;
                if (row < LQ) {
                    float o = acc[mt][nt][r] + bb;
                    if (isval) {
                        int h = col >> 5, c = col & 31;
                        value_t[((size_t)h * LIN + row) * 32 + c] = bf16_rte(o);
                    } else {
                        qbuf[(size_t)row * 512 + col] = bf16_rte(o);
                    }
                }
            }
    }
}

// -------------------------------------------------------------------------
// Final projection GEMM (r8, verified): out = samp @ Bw' + bout, fp32 out.
// -------------------------------------------------------------------------
__global__ __launch_bounds__(256) void gemm_out(
    const unsigned short* __restrict__ A, const unsigned short* __restrict__ Bt,
    const float* __restrict__ bias, float* __restrict__ Cout)
{
    __shared__ __align__(16) unsigned short As[128][40];
    __shared__ __align__(16) unsigned short Bs[128][40];

    const int t    = threadIdx.x;
    const int bm   = blockIdx.y * 128;
    const int n0   = blockIdx.x * 128;
    const int w    = t >> 6;
    const int lane = t & 63;
    const int lm   = lane & 15;
    const int quad = lane >> 4;

    const int s_row = t >> 1;
    const int s_k   = (t & 1) << 4;

    int arow_g = bm + s_row; if (arow_g >= LQ) arow_g = LQ - 1;
    const size_t a_off = (size_t)arow_g * K_DIM + s_k;
    const size_t b_off = (size_t)(n0 + s_row) * K_DIM + s_k;

    f32x4 acc[2][8];
    #pragma unroll
    for (int mt = 0; mt < 2; ++mt)
        #pragma unroll
        for (int nt = 0; nt < 8; ++nt)
            acc[mt][nt] = (f32x4){0.f, 0.f, 0.f, 0.f};

    for (int k0 = 0; k0 < K_DIM; k0 += 32) {
        int4 a0 = *(const int4*)(A + a_off + k0);
        int4 a1 = *(const int4*)(A + a_off + k0 + 8);
        int4 b0 = *(const int4*)(Bt + b_off + k0);
        int4 b1 = *(const int4*)(Bt + b_off + k0 + 8);
        __syncthreads();
        *(int4*)&As[s_row][s_k]     = a0;
        *(int4*)&As[s_row][s_k + 8] = a1;
        *(int4*)&Bs[s_row][s_k]     = b0;
        *(int4*)&Bs[s_row][s_k + 8] = b1;
        __syncthreads();

        short8 af[2], bf[8];
        #pragma unroll
        for (int mt = 0; mt < 2; ++mt)
            af[mt] = *(const short8*)&As[w * 32 + mt * 16 + lm][quad * 8];
        #pragma unroll
        for (int nt = 0; nt < 8; ++nt)
            bf[nt] = *(const short8*)&Bs[nt * 16 + lm][quad * 8];
        #pragma unroll
        for (int mt = 0; mt < 2; ++mt)
            #pragma unroll
            for (int nt = 0; nt < 8; ++nt)
                acc[mt][nt] = __builtin_amdgcn_mfma_f32_16x16x32_bf16(af[mt], bf[nt], acc[mt][nt], 0, 0, 0);
    }

    #pragma unroll
    for (int nt = 0; nt < 8; ++nt) {
        int col = n0 + nt * 16 + lm;
        float bb = bias[col];
        #pragma unroll
        for (int mt = 0; mt < 2; ++mt)
            #pragma unroll
            for (int r = 0; r < 4; ++r) {
                int row = bm + w * 32 + mt * 16 + quad * 4 + r;
                if (row < LQ)
                    Cout[(size_t)row * DMODEL + col] = acc[mt][nt][r] + bb;
            }
    }
}

// -------------------------------------------------------------------------
// Sampling kernel v5: r8's verified structure + VALU diet.
//  - SADDR gather: 32-bit unsigned offsets from uniform base vbase =
//    value_t - 64 elems (inside the 256B workspace pad) -> 1 v_add/corner.
//  - Dirty-mantissa unpack: odd channel uses raw dword as f32 (low 16 bits
//    are the even channel's bits -> <=2^-9 relative perturbation, within
//    error budget); even channel via shl. Halves unpack VALU.
// 64 lanes per query = 8 heads x 8 lanes; shfl_xor(4) x-half combine.
// -------------------------------------------------------------------------
__global__ __launch_bounds__(256) void sample_kernel(
    const float* __restrict__ refp,              // (LQ, 4, 3) fp32
    const unsigned short* __restrict__ qbuf,     // (LQ, 512) bf16
    const unsigned short* __restrict__ value_t,  // (8, LIN, 32) bf16 head-major
    unsigned short* __restrict__ samp)           // (LQ, 256) bf16
{
    __shared__ float4 zywS[4][16][8];   // zy corner cross-weights   8 KB
    __shared__ f32x2  wxS [4][16][8];   // (wx0, wx1) * a            4 KB
    __shared__ int4   ozyS[4][16][8];   // zy offsets (elements)     8 KB
    __shared__ int    xbS [4][16][8];   // x0 * 32 (elements)        2 KB
    __shared__ float  lg  [4][128];     // logits                    2 KB

    const int t  = threadIdx.x;
    const int q0 = blockIdx.x * 4;

    const int   Sz[4]   = {32, 16, 8, 4};
    const float invS[4] = {1.f/32.f, 1.f/16.f, 1.f/8.f, 1.f/4.f};
    const int   St[4]   = {0, 32768, 36864, 37376};

    // Phase 1: geometry
    #pragma unroll
    for (int pi = t; pi < 512; pi += 256) {
        int ql = pi >> 7;
        int hp = pi & 127;          // hh*16 + c, c = l*4+p
        int hh = hp >> 4;
        int c  = hp & 15;
        int l  = c >> 2;
        int q  = q0 + ql;
        const unsigned short* o = qbuf + (size_t)q * 512 + hp * 3;
        const float* r = refp + q * 12 + l * 3;
        const int   S  = Sz[l];
        const float Sf = (float)S;
        const float is = invS[l];
        float ix = (r[0] + bf16_f(o[0]) * is) * Sf - 0.5f;
        float iy = (r[1] + bf16_f(o[1]) * is) * Sf - 0.5f;
        float iz = (r[2] + bf16_f(o[2]) * is) * Sf - 0.5f;
        float xf = floorf(ix), yf = floorf(iy), zf = floorf(iz);
        float fx = ix - xf, fy = iy - yf, fz = iz - zf;
        int x0 = (int)xf, y0 = (int)yf, z0 = (int)zf;

        float wx0 = (x0 >= 0  && x0 < S)     ? (1.f - fx) : 0.f;
        float wx1 = (x0 >= -1 && x0 < S - 1) ? fx         : 0.f;
        float wy0 = (y0 >= 0  && y0 < S)     ? (1.f - fy) : 0.f;
        float wy1 = (y0 >= -1 && y0 < S - 1) ? fy         : 0.f;
        float wz0 = (z0 >= 0  && z0 < S)     ? (1.f - fz) : 0.f;
        float wz1 = (z0 >= -1 && z0 < S - 1) ? fz         : 0.f;

        int cy0 = min(max(y0, 0), S - 1), cy1 = min(max(y0 + 1, 0), S - 1);
        int cz0 = min(max(z0, 0), S - 1), cz1 = min(max(z0 + 1, 0), S - 1);

        const int S2 = S * S;
        const int st = St[l];
        zywS[ql][c][hh] = make_float4(wz0*wy0, wz0*wy1, wz1*wy0, wz1*wy1);
        wxS [ql][c][hh] = (f32x2){wx0, wx1};
        ozyS[ql][c][hh] = make_int4((st + cz0*S2 + cy0*S) * 32,
                                    (st + cz0*S2 + cy1*S) * 32,
                                    (st + cz1*S2 + cy0*S) * 32,
                                    (st + cz1*S2 + cy1*S) * 32);
        xbS [ql][c][hh] = x0 * 32;   // may be -32 .. (S-1)*32
        lg[ql][hp] = bf16_f(qbuf[(size_t)q * 512 + 384 + hp]);
    }
    __syncthreads();

    // Phase 1b: softmax over 16 points per (q_local, head); fold a into wx
    #pragma unroll
    for (int pi = t; pi < 512; pi += 256) {
        int ql = pi >> 7;
        int hp = pi & 127;
        int hh = hp >> 4;
        int c  = hp & 15;
        const float* L = &lg[ql][hh << 4];
        float m = L[0];
        #pragma unroll
        for (int j = 1; j < 16; ++j) m = fmaxf(m, L[j]);
        float s = 0.f;
        #pragma unroll
        for (int j = 0; j < 16; ++j) s += expf(L[j] - m);
        float a = expf(lg[ql][hp] - m) / s;
        f32x2 wv = wxS[ql][c][hh];
        wxS[ql][c][hh] = (f32x2){wv.x * a, wv.y * a};
    }
    __syncthreads();

    // Phase 2: gather + weighted accumulate. 64 lanes = 8 heads x 8 lanes.
    const int ql   = t >> 6;
    const int lane = t & 63;
    const int hh   = lane >> 3;
    const int j    = lane & 7;
    const int xsel = j >> 2;          // 0: x0 half, 1: x1 half
    const int cgrp = (j & 3) << 3;    // output channel group base (8 ch)
    const int q    = q0 + ql;

    // uniform base 64 elements before value_t (workspace has a 256B pad);
    // all per-corner offsets are 32-bit unsigned -> SADDR-form loads.
    const unsigned short* vbase = value_t - 64;
    const unsigned laneoff = (unsigned)(hh * (LIN * 32) + j * 8 + 64);

    f32x2 acc0 = {0.f,0.f}, acc1 = {0.f,0.f}, acc2 = {0.f,0.f}, acc3 = {0.f,0.f};

    #pragma unroll
    for (int c = 0; c < 16; ++c) {
        float4 zyw = zywS[ql][c][hh];
        f32x2  wx  = wxS [ql][c][hh];
        int4   zo  = ozyS[ql][c][hh];
        int    xb  = xbS [ql][c][hh];
        float  ws  = xsel ? wx.y : wx.x;
        const unsigned pb = laneoff + (unsigned)xb;

        #define CORNER(OFF, WZ) { \
            int4 v = *(const int4*)(vbase + (unsigned)(pb + (unsigned)(OFF))); \
            float w_ = (WZ) * ws; \
            f32x2 w2 = {w_, w_}; \
            acc0 += w2 * (f32x2){bits_f(((unsigned)v.x) << 16), bits_f((unsigned)v.x)}; \
            acc1 += w2 * (f32x2){bits_f(((unsigned)v.y) << 16), bits_f((unsigned)v.y)}; \
            acc2 += w2 * (f32x2){bits_f(((unsigned)v.z) << 16), bits_f((unsigned)v.z)}; \
            acc3 += w2 * (f32x2){bits_f(((unsigned)v.w) << 16), bits_f((unsigned)v.w)}; }

        CORNER(zo.x, zyw.x);
        CORNER(zo.y, zyw.y);
        CORNER(zo.z, zyw.z);
        CORNER(zo.w, zyw.w);
        #undef CORNER
    }

    // Combine x0/x1 halves across lane^4, pack to bf16, store (lanes j<4)
    float c0 = acc0.x + __shfl_xor(acc0.x, 4);
    float c1 = acc0.y + __shfl_xor(acc0.y, 4);
    float c2 = acc1.x + __shfl_xor(acc1.x, 4);
    float c3 = acc1.y + __shfl_xor(acc1.y, 4);
    float c4 = acc2.x + __shfl_xor(acc2.x, 4);
    float c5 = acc2.y + __shfl_xor(acc2.y, 4);
    float c6 = acc3.x + __shfl_xor(acc3.x, 4);
    float c7 = acc3.y + __shfl_xor(acc3.y, 4);
    if (xsel == 0) {
        int4 o = make_int4((int)pkbf(c0, c1), (int)pkbf(c2, c3),
                           (int)pkbf(c4, c5), (int)pkbf(c6, c7));
        *(int4*)(samp + (size_t)q * DMODEL + hh * CHEAD + cgrp) = o;
    }
}

// -------------------------------------------------------------------------
// 4 launches: prep_all, gemm2 (value+qbuf), sample_kernel, gemm_out.
// Workspace (~116 MB): pad 256B | value_t 19.2 | qbuf 38.3 | samp 19.2 |
// in_b 19.2 | q_b 19.2 | Bv/Bq/Bw/bias ~0.55 MB
// -------------------------------------------------------------------------
extern "C" void kernel_launch(void* const* d_in, const int* in_sizes, int n_in,
                              void* d_out, int out_size, void* d_ws, size_t ws_size,
                              hipStream_t stream) {
    const float* query = (const float*)d_in[0];
    const float* refp  = (const float*)d_in[1];
    const float* inp   = (const float*)d_in[2];
    const float* Wv   = (const float*)d_in[5];
    const float* bv   = (const float*)d_in[6];
    const float* Wo   = (const float*)d_in[7];
    const float* bo   = (const float*)d_in[8];
    const float* Wa   = (const float*)d_in[9];
    const float* ba   = (const float*)d_in[10];
    const float* Wout = (const float*)d_in[11];
    const float* bout = (const float*)d_in[12];

    char* p = (char*)d_ws;
    p += 256;                                     // underflow pad
    unsigned short* value_t = (unsigned short*)p; p += (size_t)LIN * 256 * 2;
    unsigned short* qbuf    = (unsigned short*)p; p += (size_t)LQ * 512 * 2;
    unsigned short* samp    = (unsigned short*)p; p += (size_t)LQ * 256 * 2;
    unsigned short* in_b    = (unsigned short*)p; p += (size_t)LQ * 256 * 2;
    unsigned short* q_b     = (unsigned short*)p; p += (size_t)LQ * 256 * 2;
    unsigned short* Bv   = (unsigned short*)p;    p += 256 * 256 * 2;
    unsigned short* Bq   = (unsigned short*)p;    p += 512 * 256 * 2;
    unsigned short* Bw   = (unsigned short*)p;    p += 256 * 256 * 2;
    float* bias_m = (float*)p;                    p += 512 * 4;

    const int n4 = LQ * 256 / 4;   // 2,396,160
    dim3 blk(256);

    // 1) all prep: activations fp32->bf16 + weight transposes + bias concat
    prep_all<<<18720 + 1024, blk, 0, stream>>>(
        inp, query, Wv, Wo, Wa, Wout, bo, ba,
        in_b, q_b, Bv, Bq, Bw, bias_m, n4);
    // 2) value (head-major) + off/attn (qbuf) in one launch
    gemm2<<<dim3(6, (LQ + 127) / 128), blk, 0, stream>>>(
        in_b, q_b, Bv, Bq, bv, bias_m, value_t, qbuf);
    // 3) sampling + softmax + weighted sum -> samp bf16
    sample_kernel<<<LQ / 4, blk, 0, stream>>>(refp, qbuf, value_t, samp);
    // 4) out = samp @ W_out + b (fp32 out)
    gemm_out<<<dim3(2, (LQ + 127) / 128), blk, 0, stream>>>(samp, Bw, bout, (float*)d_out);
}